// Round 10
// baseline (289.490 us; speedup 1.0000x reference)
//
#include <hip/hip_runtime.h>
#include <math.h>

#define NTOK 131072
#define KC   1024
#define DIMV 64
#define NWAVE 16
#define TPW  32                  // tokens per wave (2 groups of 16)
#define TPB  (NWAVE * TPW)       // 512 tokens per block
#define CMAX 128                 // per-wave candidate capacity (expect ~37)
#define EPSH 1e-3f               // EPS/2 in halved units (verified r3-r9)

#define OUT_LOSS 0
#define OUT_Q    1
#define OUT_PERP (1 + NTOK * DIMV)
#define OUT_IDX  (2 + NTOK * DIMV)

// workspace floats: [0]=mse, [1..1024]=hist, [1025]=done ticket,
// [1026..2049]=norms; packed bf16-hi fragments at byte 12288 (128 KB)
#define WS_HIST 1
#define WS_TKT  1025
#define WS_NORM 1026
#define WS_PACK_BYTES 12288

typedef __attribute__((ext_vector_type(8))) short short8;
typedef __attribute__((ext_vector_type(4))) float f32x4;

// numpy pairwise_sum mimic for n=64 of v[i]*v[i] (no FMA) — bit-identical
// to the verified kernel.
__device__ __forceinline__ float sumsq64_np(const float v[DIMV]) {
#pragma clang fp contract(off)
  {
    float r[8];
#pragma unroll
    for (int j = 0; j < 8; ++j) r[j] = v[j] * v[j];
#pragma unroll
    for (int i = 8; i < 64; i += 8) {
#pragma unroll
      for (int j = 0; j < 8; ++j) r[j] += v[i + j] * v[i + j];
    }
    return ((r[0] + r[1]) + (r[2] + r[3])) + ((r[4] + r[5]) + (r[6] + r[7]));
  }
}

__device__ __forceinline__ unsigned short bf16rne(float f) {
  unsigned int u = __float_as_uint(f);
  return (unsigned short)((u + 0x7fffu + ((u >> 16) & 1u)) >> 16);
}

// ---------------- pack: bf16-hi B-fragments + exact norms + ws zeroing -----
// (verified r7: tile t, cell f, lane l layout; zeroes mse/hist/ticket)
__global__ void __launch_bounds__(256)
vq_pack_kernel(const float* __restrict__ cb, float* __restrict__ ws) {
  const int e = blockIdx.x * 256 + threadIdx.x;   // 0..8191
  if (e < 1026) ws[e] = 0.0f;
  const int tile = e >> 7, f = (e >> 6) & 1, l = e & 63;
  const int code = tile * 16 + (l & 15);
  const int kb = f * 32 + (l >> 4) * 8;
  const float4* src = reinterpret_cast<const float4*>(cb + code * DIMV + kb);
  float4 v0 = src[0], v1 = src[1];
  float v[8] = {v0.x, v0.y, v0.z, v0.w, v1.x, v1.y, v1.z, v1.w};
  unsigned int hw[4];
#pragma unroll
  for (int j = 0; j < 4; ++j) {
    hw[j] = (unsigned int)bf16rne(v[2 * j]) |
            ((unsigned int)bf16rne(v[2 * j + 1]) << 16);
  }
  char* pack = (char*)ws + WS_PACK_BYTES;
  *(uint4*)(pack + tile * 2048 + f * 1024 + l * 16) =
      make_uint4(hw[0], hw[1], hw[2], hw[3]);
  if (e < KC) {
    float row[DIMV];
    const float4* r4 = reinterpret_cast<const float4*>(cb + e * DIMV);
#pragma unroll
    for (int i = 0; i < 16; ++i) {
      float4 t = r4[i];
      row[4 * i + 0] = t.x; row[4 * i + 1] = t.y;
      row[4 * i + 2] = t.z; row[4 * i + 3] = t.w;
    }
    ws[WS_NORM + e] = sumsq64_np(row);
  }
}

// ---------------- K1: r7 argmin pipeline; ends by publishing keys ----------
__global__ void __launch_bounds__(1024)
vq_argmin(const float* __restrict__ xin, const float* __restrict__ cb,
          float* __restrict__ out, float* __restrict__ ws) {
  __shared__ __align__(16) char s_pack[131072];       // 128 KB packed codebook
  __shared__ float s_norm[KC];
  __shared__ unsigned int s_cand[NWAVE][CMAX];
  __shared__ unsigned long long s_key[NWAVE][TPW];
  __shared__ int s_cnt[NWAVE];

  const int tid = threadIdx.x;
  const int l   = tid & 63;
  const int wv  = tid >> 6;
  const int cls = l & 15;     // code-within-tile / D-col; A-token row
  const int g   = l >> 4;     // k-subgroup / D-row group
  const int blk = blockIdx.x;
  const int tb  = blk * TPB + wv * TPW;

  const float* ws_norm = ws + WS_NORM;
  const char* pack = (const char*)ws + WS_PACK_BYTES;

  // ---- prologue: stage pack (128 KB) + norms; init keys/cnt ----
  {
    const uint4* src = (const uint4*)pack;
    uint4* dst = (uint4*)s_pack;
#pragma unroll
    for (int i = 0; i < 8; ++i) dst[tid + i * 1024] = src[tid + i * 1024];
  }
  s_norm[tid] = ws_norm[tid];
  if (tid < NWAVE * TPW) ((unsigned long long*)s_key)[tid] = ~0ull;
  if (tid < NWAVE) s_cnt[tid] = 0;
  __syncthreads();

  // A-fragments (bf16-hi) for 2 token groups: row = cls, k = kc*32 + g*8 + j
  short8 af[2][2];
#pragma unroll
  for (int grp = 0; grp < 2; ++grp) {
    const float* xr = xin + (size_t)(tb + grp * 16 + cls) * DIMV + g * 8;
#pragma unroll
    for (int kc = 0; kc < 2; ++kc) {
      float4 v0 = *(const float4*)(xr + kc * 32);
      float4 v1 = *(const float4*)(xr + kc * 32 + 4);
      float vv[8] = {v0.x, v0.y, v0.z, v0.w, v1.x, v1.y, v1.z, v1.w};
#pragma unroll
      for (int j = 0; j < 8; ++j) af[grp][kc][j] = (short)bf16rne(vv[j]);
    }
  }

  // ---------------- pass 1: per-token min of s~/2 = norm/2 - dot~ ---------
  float minv[2][4];
#pragma unroll
  for (int grp = 0; grp < 2; ++grp)
#pragma unroll
    for (int j = 0; j < 4; ++j) minv[grp][j] = INFINITY;

  short8 b0 = *(const short8*)(s_pack + l * 16);
  short8 b1 = *(const short8*)(s_pack + 1024 + l * 16);
  float nr = s_norm[cls];
#pragma unroll 2
  for (int t = 0; t < 64; ++t) {
    short8 c0 = b0, c1 = b1;
    float cc = -0.5f * nr;
    if (t < 63) {
      const char* bp = s_pack + (t + 1) * 2048 + l * 16;
      b0 = *(const short8*)(bp);
      b1 = *(const short8*)(bp + 1024);
      nr = s_norm[(t + 1) * 16 + cls];
    }
#pragma unroll
    for (int grp = 0; grp < 2; ++grp) {
      f32x4 acc = {cc, cc, cc, cc};
      acc = __builtin_amdgcn_mfma_f32_16x16x32_bf16(af[grp][0], c0, acc, 0, 0, 0);
      acc = __builtin_amdgcn_mfma_f32_16x16x32_bf16(af[grp][1], c1, acc, 0, 0, 0);
#pragma unroll
      for (int j = 0; j < 4; ++j)
        minv[grp][j] = fminf(minv[grp][j], -acc[j]);
    }
  }
#pragma unroll
  for (int mask = 1; mask < 16; mask <<= 1) {
#pragma unroll
    for (int grp = 0; grp < 2; ++grp)
#pragma unroll
      for (int j = 0; j < 4; ++j)
        minv[grp][j] = fminf(minv[grp][j], __shfl_xor(minv[grp][j], mask, 64));
  }
  float thr[2][4];
#pragma unroll
  for (int grp = 0; grp < 2; ++grp)
#pragma unroll
    for (int j = 0; j < 4; ++j) thr[grp][j] = minv[grp][j] + EPSH;

  // ---------------- pass 2: collect candidates s~/2 <= min + EPSH ---------
  b0 = *(const short8*)(s_pack + l * 16);
  b1 = *(const short8*)(s_pack + 1024 + l * 16);
  nr = s_norm[cls];
#pragma unroll 2
  for (int t = 0; t < 64; ++t) {
    short8 c0 = b0, c1 = b1;
    float cc = -0.5f * nr;
    if (t < 63) {
      const char* bp = s_pack + (t + 1) * 2048 + l * 16;
      b0 = *(const short8*)(bp);
      b1 = *(const short8*)(bp + 1024);
      nr = s_norm[(t + 1) * 16 + cls];
    }
#pragma unroll
    for (int grp = 0; grp < 2; ++grp) {
      f32x4 acc = {cc, cc, cc, cc};
      acc = __builtin_amdgcn_mfma_f32_16x16x32_bf16(af[grp][0], c0, acc, 0, 0, 0);
      acc = __builtin_amdgcn_mfma_f32_16x16x32_bf16(af[grp][1], c1, acc, 0, 0, 0);
#pragma unroll
      for (int j = 0; j < 4; ++j) {
        if (-acc[j] <= thr[grp][j]) {
          int pos = atomicAdd(&s_cnt[wv], 1);
          if (pos < CMAX)
            s_cand[wv][pos] =
                ((unsigned int)(grp * 16 + g * 4 + j) << 10) |
                (unsigned int)(t * 16 + cls);
        }
      }
    }
  }
  asm volatile("s_waitcnt lgkmcnt(0)" ::: "memory");
  const int cnt = s_cnt[wv];
  int n = cnt < CMAX ? cnt : CMAX;

  // ---------------- exact re-score (bit-identical chains) -----------------
  for (int base = 0; base < n; base += 64) {
    int i = base + l;
    if (i < n) {
      unsigned int pk = s_cand[wv][i];
      int m = (int)(pk >> 10), k = (int)(pk & 1023);
      const float4* xr4 = (const float4*)(xin + (size_t)(tb + m) * DIMV);
      const float4* er4 = (const float4*)(cb + (size_t)k * DIMV);
      float r[8];
      float dot = 0.0f;
#pragma unroll
      for (int s = 0; s < 8; ++s) {
        float4 a = xr4[2 * s], b = xr4[2 * s + 1];
        float4 ea = er4[2 * s], eb = er4[2 * s + 1];
        float xv[8] = {a.x, a.y, a.z, a.w, b.x, b.y, b.z, b.w};
        float ev[8] = {ea.x, ea.y, ea.z, ea.w, eb.x, eb.y, eb.z, eb.w};
        {
#pragma clang fp contract(off)
#pragma unroll
          for (int j = 0; j < 8; ++j) {
            float sq = xv[j] * xv[j];
            r[j] = (s == 0) ? sq : (r[j] + sq);
          }
        }
#pragma unroll
        for (int j = 0; j < 8; ++j) dot = __builtin_fmaf(ev[j], xv[j], dot);
      }
      float xx = ((r[0] + r[1]) + (r[2] + r[3])) + ((r[4] + r[5]) + (r[6] + r[7]));
      float d = (xx - 2.0f * dot) + s_norm[k];
      unsigned long long key =
          ((unsigned long long)__float_as_uint(d) << 10) | (unsigned long long)k;
      atomicMin(&s_key[wv][m], key);
    }
  }

  // safety net (never expected): candidate overflow -> exact full scan
  if (cnt > CMAX) {
    asm volatile("s_waitcnt lgkmcnt(0)" ::: "memory");
    if (l < TPW) {
      const int m = l;
      float xv[DIMV];
      const float4* xr4 = (const float4*)(xin + (size_t)(tb + m) * DIMV);
#pragma unroll
      for (int i = 0; i < 16; ++i) {
        float4 t4 = xr4[i];
        xv[4 * i + 0] = t4.x; xv[4 * i + 1] = t4.y;
        xv[4 * i + 2] = t4.z; xv[4 * i + 3] = t4.w;
      }
      float xx = sumsq64_np(xv);
      float bd = INFINITY; int bk = 0;
      for (int k = 0; k < KC; ++k) {
        const float* e = cb + (size_t)k * DIMV;
        float dot = 0.0f;
#pragma unroll
        for (int i = 0; i < DIMV; ++i) dot = __builtin_fmaf(e[i], xv[i], dot);
        float d = (xx - 2.0f * dot) + s_norm[k];
        if (d < bd) { bd = d; bk = k; }
      }
      s_key[wv][m] =
          ((unsigned long long)__float_as_uint(bd) << 10) | (unsigned long long)bk;
    }
  }
  __syncthreads();   // all waves' keys final (cross-wave publish below)

  // ---- publish keys into bytes [8,16) of each token's quantized row ------
  // (8-aligned; r8 proved slot-in-out correctness; K2 overwrites the row)
  if (tid < TPB) {
    const int token = blk * TPB + tid;
    *(unsigned long long*)((char*)out + 8 + (size_t)token * 256) =
        ((unsigned long long*)s_key)[tid];
  }
}

// ---------------- K2: streaming epilogue, 4 threads/token ------------------
__global__ void __launch_bounds__(256)
vq_epilogue(const float* __restrict__ xin, const float* __restrict__ cb,
            float* __restrict__ out, float* __restrict__ ws) {
  __shared__ unsigned int s_hist[KC];
  __shared__ float s_red[256];
  __shared__ int s_flag;
  const int tid = threadIdx.x;
  const int l   = tid & 63;

  float* ws_mse = ws;
  unsigned int* ws_hist = (unsigned int*)ws + WS_HIST;
  unsigned int* ws_done = (unsigned int*)ws + WS_TKT;

  for (int k = tid; k < KC; k += 256) s_hist[k] = 0u;
  __syncthreads();

  const int tok = blockIdx.x * 64 + (tid >> 2);   // 64 tokens/block
  const int sub = tid & 3;
  // key read: address-dependency of the q4 loads on `key` orders the row
  // overwrite after this read within the wave (4 lanes/token, same wave).
  unsigned long long key =
      *(const unsigned long long*)((const char*)out + 8 + (size_t)tok * 256);
  const int bk = (int)(key & 1023ull);
  if (sub == 0) {
    out[OUT_IDX + tok] = (float)bk;
    atomicAdd(&s_hist[bk], 1u);
  }
  // verified epilogue math (r9, absmax 0.0): 16 floats per thread
  const float4* q4 = (const float4*)(cb + (size_t)bk * DIMV + sub * 16);
  const float4* x4 = (const float4*)(xin + (size_t)tok * DIMV + sub * 16);
  float* oq = out + OUT_Q + (size_t)tok * DIMV + sub * 16;
  float mse_part = 0.0f;
#pragma unroll
  for (int rr = 0; rr < 4; ++rr) {
    float4 qv = q4[rr], xv = x4[rr];
    float d0 = qv.x - xv.x, d1 = qv.y - xv.y;
    float d2 = qv.z - xv.z, d3 = qv.w - xv.w;
    float4 o;
    o.x = xv.x + d0; o.y = xv.y + d1; o.z = xv.z + d2; o.w = xv.w + d3;
    mse_part = __builtin_fmaf(d0, d0, mse_part);
    mse_part = __builtin_fmaf(d1, d1, mse_part);
    mse_part = __builtin_fmaf(d2, d2, mse_part);
    mse_part = __builtin_fmaf(d3, d3, mse_part);
    *(float4*)(oq + 4 * rr) = o;
  }
#pragma unroll
  for (int mask = 1; mask < 64; mask <<= 1)
    mse_part += __shfl_xor(mse_part, mask, 64);
  if (l == 0) atomicAdd(ws_mse, mse_part);

  __syncthreads();   // s_hist atomics done
  for (int k = tid; k < KC; k += 256) {
    unsigned int c = s_hist[k];
    if (c) atomicAdd(&ws_hist[k], c);
  }
  __syncthreads();   // global hist atomics drained at barrier

  // ---- last-block final: perplexity + loss (verified ticket pattern) -----
  if (tid == 0) {
    __threadfence();
    unsigned int tkt = atomicAdd(ws_done, 1u);
    s_flag = (tkt == (unsigned int)(gridDim.x - 1)) ? 1 : 0;
  }
  __syncthreads();
  if (s_flag) {
    __threadfence();
    float term = 0.0f;
    for (int k = tid; k < KC; k += 256) {
      unsigned int c = atomicAdd(&ws_hist[k], 0u);   // coherent read
      float p = (float)c / 131072.0f;                // exact (2^17)
      term += p * logf(p + 1e-10f);                  // p==0 -> 0
    }
    s_red[tid] = term;
    __syncthreads();
#pragma unroll
    for (int s = 128; s > 0; s >>= 1) {
      if (tid < s) s_red[tid] += s_red[tid + s];
      __syncthreads();
    }
    if (tid == 0) {
      out[OUT_PERP] = expf(-s_red[0]);
      float mse = atomicAdd(ws_mse, 0.0f) / 8388608.0f;   // exact (2^23)
      out[OUT_LOSS] = mse + 0.25f * mse;
    }
  }
}

extern "C" void kernel_launch(void* const* d_in, const int* in_sizes, int n_in,
                              void* d_out, int out_size, void* d_ws, size_t ws_size,
                              hipStream_t stream) {
  (void)in_sizes; (void)n_in; (void)out_size; (void)ws_size;
  const float* xin = (const float*)d_in[0];
  const float* cb  = (const float*)d_in[1];
  float* out = (float*)d_out;
  float* ws  = (float*)d_ws;

  hipLaunchKernelGGL(vq_pack_kernel, dim3(32), dim3(256), 0, stream, cb, ws);
  hipLaunchKernelGGL(vq_argmin, dim3(NTOK / TPB), dim3(1024), 0, stream,
                     xin, cb, out, ws);
  hipLaunchKernelGGL(vq_epilogue, dim3(NTOK / 64), dim3(256), 0, stream,
                     xin, cb, out, ws);
}

// Round 11
// 189.367 us; speedup vs baseline: 1.5287x; 1.5287x over previous
//
#include <hip/hip_runtime.h>
#include <math.h>

#define NTOK 131072
#define KC   1024
#define DIMV 64
#define NWAVE 16
#define TPW  32                  // tokens per wave (2 groups of 16)
#define TPB  (NWAVE * TPW)       // 512 tokens per block
#define CMAX 128                 // per-wave candidate capacity (expect ~37)
#define EPSH 1e-3f               // EPS/2 in halved units (verified r3-r10)

#define OUT_LOSS 0
#define OUT_Q    1
#define OUT_PERP (1 + NTOK * DIMV)
#define OUT_IDX  (2 + NTOK * DIMV)

// workspace floats: [0]=mse, [1..1024]=hist, [1025]=done ticket,
// [1026..2049]=norms; packed bf16-hi fragments at byte 12288 (128 KB)
#define WS_HIST 1
#define WS_TKT  1025
#define WS_NORM 1026
#define WS_PACK_BYTES 12288

typedef __attribute__((ext_vector_type(8))) short short8;
typedef __attribute__((ext_vector_type(4))) float f32x4;

// numpy pairwise_sum mimic for n=64 of v[i]*v[i] (no FMA) — bit-identical
// to the verified kernel.
__device__ __forceinline__ float sumsq64_np(const float v[DIMV]) {
#pragma clang fp contract(off)
  {
    float r[8];
#pragma unroll
    for (int j = 0; j < 8; ++j) r[j] = v[j] * v[j];
#pragma unroll
    for (int i = 8; i < 64; i += 8) {
#pragma unroll
      for (int j = 0; j < 8; ++j) r[j] += v[i + j] * v[i + j];
    }
    return ((r[0] + r[1]) + (r[2] + r[3])) + ((r[4] + r[5]) + (r[6] + r[7]));
  }
}

__device__ __forceinline__ unsigned short bf16rne(float f) {
  unsigned int u = __float_as_uint(f);
  return (unsigned short)((u + 0x7fffu + ((u >> 16) & 1u)) >> 16);
}

// ---------------- pack: bf16-hi B-fragments + exact norms + ws zeroing -----
// (verified r7-r10: tile t, cell f, lane l layout; zeroes mse/hist/ticket)
__global__ void __launch_bounds__(256)
vq_pack_kernel(const float* __restrict__ cb, float* __restrict__ ws) {
  const int e = blockIdx.x * 256 + threadIdx.x;   // 0..8191
  if (e < 1026) ws[e] = 0.0f;
  const int tile = e >> 7, f = (e >> 6) & 1, l = e & 63;
  const int code = tile * 16 + (l & 15);
  const int kb = f * 32 + (l >> 4) * 8;
  const float4* src = reinterpret_cast<const float4*>(cb + code * DIMV + kb);
  float4 v0 = src[0], v1 = src[1];
  float v[8] = {v0.x, v0.y, v0.z, v0.w, v1.x, v1.y, v1.z, v1.w};
  unsigned int hw[4];
#pragma unroll
  for (int j = 0; j < 4; ++j) {
    hw[j] = (unsigned int)bf16rne(v[2 * j]) |
            ((unsigned int)bf16rne(v[2 * j + 1]) << 16);
  }
  char* pack = (char*)ws + WS_PACK_BYTES;
  *(uint4*)(pack + tile * 2048 + f * 1024 + l * 16) =
      make_uint4(hw[0], hw[1], hw[2], hw[3]);
  if (e < KC) {
    float row[DIMV];
    const float4* r4 = reinterpret_cast<const float4*>(cb + e * DIMV);
#pragma unroll
    for (int i = 0; i < 16; ++i) {
      float4 t = r4[i];
      row[4 * i + 0] = t.x; row[4 * i + 1] = t.y;
      row[4 * i + 2] = t.z; row[4 * i + 3] = t.w;
    }
    ws[WS_NORM + e] = sumsq64_np(row);
  }
}

// ---------------- K1: verified argmin pipeline; writes OUT_IDX -------------
__global__ void __launch_bounds__(1024)
vq_argmin(const float* __restrict__ xin, const float* __restrict__ cb,
          float* __restrict__ out, float* __restrict__ ws) {
  __shared__ __align__(16) char s_pack[131072];       // 128 KB packed codebook
  __shared__ float s_norm[KC];
  __shared__ unsigned int s_cand[NWAVE][CMAX];
  __shared__ unsigned long long s_key[NWAVE][TPW];
  __shared__ int s_cnt[NWAVE];

  const int tid = threadIdx.x;
  const int l   = tid & 63;
  const int wv  = tid >> 6;
  const int cls = l & 15;     // code-within-tile / D-col; A-token row
  const int g   = l >> 4;     // k-subgroup / D-row group
  const int blk = blockIdx.x;
  const int tb  = blk * TPB + wv * TPW;

  const float* ws_norm = ws + WS_NORM;
  const char* pack = (const char*)ws + WS_PACK_BYTES;

  // ---- prologue: stage pack (128 KB) + norms; init keys/cnt ----
  {
    const uint4* src = (const uint4*)pack;
    uint4* dst = (uint4*)s_pack;
#pragma unroll
    for (int i = 0; i < 8; ++i) dst[tid + i * 1024] = src[tid + i * 1024];
  }
  s_norm[tid] = ws_norm[tid];
  if (tid < NWAVE * TPW) ((unsigned long long*)s_key)[tid] = ~0ull;
  if (tid < NWAVE) s_cnt[tid] = 0;
  __syncthreads();

  // A-fragments (bf16-hi) for 2 token groups: row = cls, k = kc*32 + g*8 + j
  short8 af[2][2];
#pragma unroll
  for (int grp = 0; grp < 2; ++grp) {
    const float* xr = xin + (size_t)(tb + grp * 16 + cls) * DIMV + g * 8;
#pragma unroll
    for (int kc = 0; kc < 2; ++kc) {
      float4 v0 = *(const float4*)(xr + kc * 32);
      float4 v1 = *(const float4*)(xr + kc * 32 + 4);
      float vv[8] = {v0.x, v0.y, v0.z, v0.w, v1.x, v1.y, v1.z, v1.w};
#pragma unroll
      for (int j = 0; j < 8; ++j) af[grp][kc][j] = (short)bf16rne(vv[j]);
    }
  }

  // ---------------- pass 1: per-token min of s~/2 = norm/2 - dot~ ---------
  float minv[2][4];
#pragma unroll
  for (int grp = 0; grp < 2; ++grp)
#pragma unroll
    for (int j = 0; j < 4; ++j) minv[grp][j] = INFINITY;

  short8 b0 = *(const short8*)(s_pack + l * 16);
  short8 b1 = *(const short8*)(s_pack + 1024 + l * 16);
  float nr = s_norm[cls];
#pragma unroll 2
  for (int t = 0; t < 64; ++t) {
    short8 c0 = b0, c1 = b1;
    float cc = -0.5f * nr;
    if (t < 63) {
      const char* bp = s_pack + (t + 1) * 2048 + l * 16;
      b0 = *(const short8*)(bp);
      b1 = *(const short8*)(bp + 1024);
      nr = s_norm[(t + 1) * 16 + cls];
    }
#pragma unroll
    for (int grp = 0; grp < 2; ++grp) {
      f32x4 acc = {cc, cc, cc, cc};
      acc = __builtin_amdgcn_mfma_f32_16x16x32_bf16(af[grp][0], c0, acc, 0, 0, 0);
      acc = __builtin_amdgcn_mfma_f32_16x16x32_bf16(af[grp][1], c1, acc, 0, 0, 0);
#pragma unroll
      for (int j = 0; j < 4; ++j)
        minv[grp][j] = fminf(minv[grp][j], -acc[j]);
    }
  }
#pragma unroll
  for (int mask = 1; mask < 16; mask <<= 1) {
#pragma unroll
    for (int grp = 0; grp < 2; ++grp)
#pragma unroll
      for (int j = 0; j < 4; ++j)
        minv[grp][j] = fminf(minv[grp][j], __shfl_xor(minv[grp][j], mask, 64));
  }
  float thr[2][4];
#pragma unroll
  for (int grp = 0; grp < 2; ++grp)
#pragma unroll
    for (int j = 0; j < 4; ++j) thr[grp][j] = minv[grp][j] + EPSH;

  // ---------------- pass 2: collect candidates s~/2 <= min + EPSH ---------
  b0 = *(const short8*)(s_pack + l * 16);
  b1 = *(const short8*)(s_pack + 1024 + l * 16);
  nr = s_norm[cls];
#pragma unroll 2
  for (int t = 0; t < 64; ++t) {
    short8 c0 = b0, c1 = b1;
    float cc = -0.5f * nr;
    if (t < 63) {
      const char* bp = s_pack + (t + 1) * 2048 + l * 16;
      b0 = *(const short8*)(bp);
      b1 = *(const short8*)(bp + 1024);
      nr = s_norm[(t + 1) * 16 + cls];
    }
#pragma unroll
    for (int grp = 0; grp < 2; ++grp) {
      f32x4 acc = {cc, cc, cc, cc};
      acc = __builtin_amdgcn_mfma_f32_16x16x32_bf16(af[grp][0], c0, acc, 0, 0, 0);
      acc = __builtin_amdgcn_mfma_f32_16x16x32_bf16(af[grp][1], c1, acc, 0, 0, 0);
#pragma unroll
      for (int j = 0; j < 4; ++j) {
        if (-acc[j] <= thr[grp][j]) {
          int pos = atomicAdd(&s_cnt[wv], 1);
          if (pos < CMAX)
            s_cand[wv][pos] =
                ((unsigned int)(grp * 16 + g * 4 + j) << 10) |
                (unsigned int)(t * 16 + cls);
        }
      }
    }
  }
  asm volatile("s_waitcnt lgkmcnt(0)" ::: "memory");
  const int cnt = s_cnt[wv];
  int n = cnt < CMAX ? cnt : CMAX;

  // ---------------- exact re-score (bit-identical chains) -----------------
  for (int base = 0; base < n; base += 64) {
    int i = base + l;
    if (i < n) {
      unsigned int pk = s_cand[wv][i];
      int m = (int)(pk >> 10), k = (int)(pk & 1023);
      const float4* xr4 = (const float4*)(xin + (size_t)(tb + m) * DIMV);
      const float4* er4 = (const float4*)(cb + (size_t)k * DIMV);
      float r[8];
      float dot = 0.0f;
#pragma unroll
      for (int s = 0; s < 8; ++s) {
        float4 a = xr4[2 * s], b = xr4[2 * s + 1];
        float4 ea = er4[2 * s], eb = er4[2 * s + 1];
        float xv[8] = {a.x, a.y, a.z, a.w, b.x, b.y, b.z, b.w};
        float ev[8] = {ea.x, ea.y, ea.z, ea.w, eb.x, eb.y, eb.z, eb.w};
        {
#pragma clang fp contract(off)
#pragma unroll
          for (int j = 0; j < 8; ++j) {
            float sq = xv[j] * xv[j];
            r[j] = (s == 0) ? sq : (r[j] + sq);
          }
        }
#pragma unroll
        for (int j = 0; j < 8; ++j) dot = __builtin_fmaf(ev[j], xv[j], dot);
      }
      float xx = ((r[0] + r[1]) + (r[2] + r[3])) + ((r[4] + r[5]) + (r[6] + r[7]));
      float d = (xx - 2.0f * dot) + s_norm[k];
      unsigned long long key =
          ((unsigned long long)__float_as_uint(d) << 10) | (unsigned long long)k;
      atomicMin(&s_key[wv][m], key);
    }
  }

  // safety net (never expected): candidate overflow -> exact full scan
  if (cnt > CMAX) {
    asm volatile("s_waitcnt lgkmcnt(0)" ::: "memory");
    if (l < TPW) {
      const int m = l;
      float xv[DIMV];
      const float4* xr4 = (const float4*)(xin + (size_t)(tb + m) * DIMV);
#pragma unroll
      for (int i = 0; i < 16; ++i) {
        float4 t4 = xr4[i];
        xv[4 * i + 0] = t4.x; xv[4 * i + 1] = t4.y;
        xv[4 * i + 2] = t4.z; xv[4 * i + 3] = t4.w;
      }
      float xx = sumsq64_np(xv);
      float bd = INFINITY; int bk = 0;
      for (int k = 0; k < KC; ++k) {
        const float* e = cb + (size_t)k * DIMV;
        float dot = 0.0f;
#pragma unroll
        for (int i = 0; i < DIMV; ++i) dot = __builtin_fmaf(e[i], xv[i], dot);
        float d = (xx - 2.0f * dot) + s_norm[k];
        if (d < bd) { bd = d; bk = k; }
      }
      s_key[wv][m] =
          ((unsigned long long)__float_as_uint(bd) << 10) | (unsigned long long)bk;
    }
  }
  __syncthreads();   // all waves' keys final

  // ---- write final indices (coalesced 512-float block write) -------------
  if (tid < TPB) {
    out[OUT_IDX + blk * TPB + tid] =
        (float)(((unsigned long long*)s_key)[tid] & 1023ull);
  }
}

// ---------------- K2: wave-coalesced streaming epilogue --------------------
// 4 consecutive tokens per wave-instruction: lane l covers bytes
// [l*16, l*16+16) of a 1024-B span -> fully coalesced loads/stores.
__global__ void __launch_bounds__(256)
vq_epilogue(const float* __restrict__ xin, const float* __restrict__ cb,
            float* __restrict__ out, float* __restrict__ ws) {
  __shared__ unsigned int s_hist[KC];
  __shared__ float s_red[256];
  __shared__ int s_flag;
  const int tid = threadIdx.x;
  const int l   = tid & 63;
  const int wvid = tid >> 6;
  const int sub = l & 15;      // element chunk within token row (4 floats)
  const int tg  = l >> 4;      // token within 4-token group

  float* ws_mse = ws;
  unsigned int* ws_hist = (unsigned int*)ws + WS_HIST;
  unsigned int* ws_done = (unsigned int*)ws + WS_TKT;

  for (int k = tid; k < KC; k += 256) s_hist[k] = 0u;
  __syncthreads();

  const int base = blockIdx.x * 256 + wvid * 64;   // 64 tokens per wave
  float mse_part = 0.0f;
#pragma unroll 4
  for (int i = 0; i < 16; ++i) {
    const int token = base + i * 4 + tg;
    const int bk = (int)out[OUT_IDX + token];
    if (sub == 0) atomicAdd(&s_hist[bk], 1u);
    // verified per-element epilogue math (absmax 0.0, r4-r10)
    float4 qv = *(const float4*)(cb + (size_t)bk * DIMV + sub * 4);
    float4 xv = *(const float4*)(xin + (size_t)token * DIMV + sub * 4);
    float d0 = qv.x - xv.x, d1 = qv.y - xv.y;
    float d2 = qv.z - xv.z, d3 = qv.w - xv.w;
    float4 o;
    o.x = xv.x + d0; o.y = xv.y + d1; o.z = xv.z + d2; o.w = xv.w + d3;
    mse_part = __builtin_fmaf(d0, d0, mse_part);
    mse_part = __builtin_fmaf(d1, d1, mse_part);
    mse_part = __builtin_fmaf(d2, d2, mse_part);
    mse_part = __builtin_fmaf(d3, d3, mse_part);
    *(float4*)(out + OUT_Q + (size_t)token * DIMV + sub * 4) = o;
  }
#pragma unroll
  for (int mask = 1; mask < 64; mask <<= 1)
    mse_part += __shfl_xor(mse_part, mask, 64);
  if (l == 0) atomicAdd(ws_mse, mse_part);

  __syncthreads();   // s_hist atomics done
  for (int k = tid; k < KC; k += 256) {
    unsigned int c = s_hist[k];
    if (c) atomicAdd(&ws_hist[k], c);
  }
  __syncthreads();   // global hist atomics drained at barrier

  // ---- last-block final: perplexity + loss (verified ticket pattern) -----
  if (tid == 0) {
    __threadfence();
    unsigned int tkt = atomicAdd(ws_done, 1u);
    s_flag = (tkt == (unsigned int)(gridDim.x - 1)) ? 1 : 0;
  }
  __syncthreads();
  if (s_flag) {
    __threadfence();
    float term = 0.0f;
    for (int k = tid; k < KC; k += 256) {
      unsigned int c = atomicAdd(&ws_hist[k], 0u);   // coherent read
      float p = (float)c / 131072.0f;                // exact (2^17)
      term += p * logf(p + 1e-10f);                  // p==0 -> 0
    }
    s_red[tid] = term;
    __syncthreads();
#pragma unroll
    for (int s = 128; s > 0; s >>= 1) {
      if (tid < s) s_red[tid] += s_red[tid + s];
      __syncthreads();
    }
    if (tid == 0) {
      out[OUT_PERP] = expf(-s_red[0]);
      float mse = atomicAdd(ws_mse, 0.0f) / 8388608.0f;   // exact (2^23)
      out[OUT_LOSS] = mse + 0.25f * mse;
    }
  }
}

extern "C" void kernel_launch(void* const* d_in, const int* in_sizes, int n_in,
                              void* d_out, int out_size, void* d_ws, size_t ws_size,
                              hipStream_t stream) {
  (void)in_sizes; (void)n_in; (void)out_size; (void)ws_size;
  const float* xin = (const float*)d_in[0];
  const float* cb  = (const float*)d_in[1];
  float* out = (float*)d_out;
  float* ws  = (float*)d_ws;

  hipLaunchKernelGGL(vq_pack_kernel, dim3(32), dim3(256), 0, stream, cb, ws);
  hipLaunchKernelGGL(vq_argmin, dim3(NTOK / TPB), dim3(1024), 0, stream,
                     xin, cb, out, ws);
  hipLaunchKernelGGL(vq_epilogue, dim3(NTOK / 256), dim3(256), 0, stream,
                     xin, cb, out, ws);
}